// Round 3
// baseline (202.714 us; speedup 1.0000x reference)
//
#include <hip/hip_runtime.h>

#define LOG2E 1.4426950408889634f
#define ROWS  32                 // rows per tile
#define BLK   128                // threads per block (2 waves)
#define PREDF (ROWS * 132)       // 4224 floats of pred per tile
#define SCOR4 (ROWS * 20)        // 640 float4 of scores/out per tile

typedef __attribute__((address_space(3))) unsigned int lds_u32_t;
typedef const __attribute__((address_space(1))) unsigned int glb_u32_t;

// Stage one tile's pred (4224 floats) into LDS: per wave exactly 9 global_load_lds
// (8 x width16 covering 512 f4 + 1 x width4 covering the last 64 floats).
__device__ __forceinline__ void stage_pred(const float* gp, float* buf, int wv, int lane) {
#pragma unroll
    for (int k = 0; k < 8; ++k) {
        const int f4 = wv * 528 + 64 * k;                     // wave-uniform f4 base
        __builtin_amdgcn_global_load_lds((glb_u32_t*)(gp + 4 * f4 + 4 * lane),
                                         (lds_u32_t*)(buf + 4 * f4), 16, 0, 0);
    }
    const int fb = (wv * 528 + 512) * 4;                      // float index of tail
    __builtin_amdgcn_global_load_lds((glb_u32_t*)(gp + fb + lane),
                                     (lds_u32_t*)(buf + fb), 4, 0, 0);
}

__global__ __launch_bounds__(BLK, 2) void lqe_pipe(
    const float* __restrict__ scores,
    const float* __restrict__ pred,
    const float* __restrict__ w1,   // [20][64]
    const float* __restrict__ b1,   // [64]
    const float* __restrict__ w2,   // [64]
    const float* __restrict__ b2,   // [1]
    float* __restrict__ out,
    int ntiles)
{
    __shared__ float predS[2][PREDF];   // 33792 B double-buffered
    __shared__ float wS[1412];          // w1[0..1279] b1[1280..1343] w2[1344..1407] b2[1408]
    __shared__ float qS[2][ROWS];       // per-row quality, double-buffered

    const int t    = threadIdx.x;
    const int lane = t & 63;
    const int wv   = t >> 6;

    // ---- one-time: stage MLP params ----
    for (int k = t; k < 1280; k += BLK) wS[k] = w1[k];
    if (t < 64) { wS[1280 + t] = b1[t]; wS[1344 + t] = w2[t]; }
    if (t == 0) wS[1408] = b2[0];
    __syncthreads();                    // drains everything; pipeline starts clean

    const int stride = gridDim.x;
    int cur = 0;

    // prologue: stage first tile into buf0 (9 gll/wave outstanding entering the loop)
    stage_pred(pred + (size_t)blockIdx.x * PREDF, &predS[0][0], wv, lane);

    for (int tile = blockIdx.x; tile < ntiles; tile += stride) {
        // clamp keeps 9 gll/wave uniform on the last iteration (harmless re-stage)
        const int nt = (tile + stride < ntiles) ? (tile + stride) : tile;

        // ---- R1: scores reg-prefetch (5 loads) + stage next tile (9 gll) ----
        const float4* sp = reinterpret_cast<const float4*>(scores) + (size_t)tile * SCOR4;
        float4 sv0 = sp[t +   0], sv1 = sp[t + 128], sv2 = sp[t + 256],
               sv3 = sp[t + 384], sv4 = sp[t + 512];
        stage_pred(pred + (size_t)nt * PREDF, &predS[cur ^ 1][0], wv, lane);

        // Outstanding (oldest->newest): pred_j(9) [, stores_{j-1}(5)] , R1: sv(5)+pred_{j+1}(9).
        // vmcnt decrements in issue order -> waiting to <=14 retires pred_j (and any
        // older stores) while keeping sv + next-tile staging in flight across the barrier.
        asm volatile("s_waitcnt vmcnt(14)" ::: "memory");
        __builtin_amdgcn_sched_barrier(0);
        __builtin_amdgcn_s_barrier();

        // ---- compute: thread (r=t>>2, c=t&3) owns one corner of one row ----
        const int r = t >> 2, c = t & 3;
        const float* xp = &predS[cur][0] + r * 132 + c * 33;   // bank = (lane+j)%32 -> 2-way, free
        float xs[33];
#pragma unroll
        for (int j = 0; j < 33; ++j) xs[j] = xp[j];

        float t0 = -1e30f, t1 = -1e30f, t2 = -1e30f, t3 = -1e30f;
#pragma unroll
        for (int j = 0; j < 33; ++j) {
            float v  = xs[j];
            float r0 = fminf(t0, v);  t0 = fmaxf(t0, v);
            float r1 = fminf(t1, r0); t1 = fmaxf(t1, r0);
            float r2 = fminf(t2, r1); t2 = fmaxf(t2, r1);
            t3 = fmaxf(t3, r2);
        }
        float denom = 0.f;
#pragma unroll
        for (int j = 0; j < 33; ++j)
            denom += __builtin_amdgcn_exp2f((xs[j] - t0) * LOG2E);
        float rd = __builtin_amdgcn_rcpf(denom);

        float s5[5];
        s5[0] = rd;
        s5[1] = __builtin_amdgcn_exp2f((t1 - t0) * LOG2E) * rd;
        s5[2] = __builtin_amdgcn_exp2f((t2 - t0) * LOG2E) * rd;
        s5[3] = __builtin_amdgcn_exp2f((t3 - t0) * LOG2E) * rd;
        s5[4] = (s5[0] + s5[1] + s5[2] + s5[3]) * 0.25f;

        // quad-local exchange: every thread gets all 20 stats of its row
        const int qbase = lane & ~3;
        float stat[20];
#pragma unroll
        for (int i = 0; i < 20; ++i)
            stat[i] = __shfl(s5[i % 5], qbase + i / 5, 64);

        // MLP: thread c computes hidden units [16c..16c+15]
        float hacc[16];
        {
            const float4* b1v = reinterpret_cast<const float4*>(wS + 1280 + 16 * c);
#pragma unroll
            for (int k = 0; k < 4; ++k) {
                float4 b = b1v[k];
                hacc[4*k+0]=b.x; hacc[4*k+1]=b.y; hacc[4*k+2]=b.z; hacc[4*k+3]=b.w;
            }
        }
#pragma unroll
        for (int i = 0; i < 20; ++i) {
            const float si = stat[i];
            const float4* wv4 = reinterpret_cast<const float4*>(wS + i * 64 + 16 * c);
#pragma unroll
            for (int k = 0; k < 4; ++k) {
                float4 w = wv4[k];
                hacc[4*k+0] = fmaf(si, w.x, hacc[4*k+0]);
                hacc[4*k+1] = fmaf(si, w.y, hacc[4*k+1]);
                hacc[4*k+2] = fmaf(si, w.z, hacc[4*k+2]);
                hacc[4*k+3] = fmaf(si, w.w, hacc[4*k+3]);
            }
        }
        float q = 0.f;
        {
            const float4* w2v = reinterpret_cast<const float4*>(wS + 1344 + 16 * c);
#pragma unroll
            for (int k = 0; k < 4; ++k) {
                float4 w = w2v[k];
#pragma unroll
                for (int e = 0; e < 4; ++e) {
                    float v  = hacc[4*k+e];
                    float sg = __builtin_amdgcn_rcpf(1.f + __builtin_amdgcn_exp2f(-v * LOG2E));
                    float we = (e == 0) ? w.x : (e == 1) ? w.y : (e == 2) ? w.z : w.w;
                    q = fmaf(v * sg, we, q);
                }
            }
        }
        q += __shfl_xor(q, 1, 64);
        q += __shfl_xor(q, 2, 64);
        q += wS[1408];
        if (c == 0) qS[cur][r] = q;

        // qS visible to all waves; all predS[cur] reads retired (lgkm drained)
        asm volatile("s_waitcnt lgkmcnt(0)" ::: "memory");
        __builtin_amdgcn_sched_barrier(0);
        __builtin_amdgcn_s_barrier();

        // ---- epilogue: coalesced out = scores + q (sv arrived long ago) ----
        float4* op = reinterpret_cast<float4*>(out) + (size_t)tile * SCOR4;
        {
            float qq;
            qq = qS[cur][(t +   0) / 20]; sv0.x+=qq; sv0.y+=qq; sv0.z+=qq; sv0.w+=qq; op[t +   0] = sv0;
            qq = qS[cur][(t + 128) / 20]; sv1.x+=qq; sv1.y+=qq; sv1.z+=qq; sv1.w+=qq; op[t + 128] = sv1;
            qq = qS[cur][(t + 256) / 20]; sv2.x+=qq; sv2.y+=qq; sv2.z+=qq; sv2.w+=qq; op[t + 256] = sv2;
            qq = qS[cur][(t + 384) / 20]; sv3.x+=qq; sv3.y+=qq; sv3.z+=qq; sv3.w+=qq; op[t + 384] = sv3;
            qq = qS[cur][(t + 512) / 20]; sv4.x+=qq; sv4.y+=qq; sv4.z+=qq; sv4.w+=qq; op[t + 512] = sv4;
        }
        cur ^= 1;
    }
}

extern "C" void kernel_launch(void* const* d_in, const int* in_sizes, int n_in,
                              void* d_out, int out_size, void* d_ws, size_t ws_size,
                              hipStream_t stream) {
    const float* scores = (const float*)d_in[0];
    const float* pred   = (const float*)d_in[1];
    const float* w1     = (const float*)d_in[2];
    const float* b1     = (const float*)d_in[3];
    const float* w2     = (const float*)d_in[4];
    const float* b2     = (const float*)d_in[5];
    float* out = (float*)d_out;

    const int nrows  = in_sizes[1] / 132;   // 800000
    const int ntiles = nrows / ROWS;        // 25000
    const int grid   = 1024;                // 4 blocks/CU x 256 CU

    hipLaunchKernelGGL(lqe_pipe, dim3(grid), dim3(BLK), 0, stream,
                       scores, pred, w1, b1, w2, b2, out, ntiles);
}

// Round 4
// 172.544 us; speedup vs baseline: 1.1749x; 1.1749x over previous
//
#include <hip/hip_runtime.h>

#define LOG2E 1.4426950408889634f

typedef __attribute__((address_space(3))) unsigned int lds_u32_t;
typedef const __attribute__((address_space(1))) unsigned int glb_u32_t;

// Block = 256 threads = 4 independent waves. Each wave owns 16 rows:
//   - stages its rows' pred (16*132 = 2112 floats, contiguous) into its own LDS chunk
//   - per-wave s_waitcnt vmcnt(0) -- NO block barrier in the hot path
//   - 4 threads per row (one per corner), quad shuffles for exchange
//   - writes its own rows' out = scores + q
__global__ __launch_bounds__(256) void lqe_wave(
    const float* __restrict__ scores,
    const float* __restrict__ pred,
    const float* __restrict__ w1,   // [20][64]
    const float* __restrict__ b1,   // [64]
    const float* __restrict__ w2,   // [64]
    const float* __restrict__ b2,   // [1]
    float* __restrict__ out)
{
    __shared__ __align__(16) float predS[4 * 2112];  // 33792 B, linear per-wave chunks
    __shared__ __align__(16) float wS[1412];         // w1[0..1279] b1[1280..] w2[1344..] b2[1408]

    const int t    = threadIdx.x;
    const int lane = t & 63;
    const int wv   = t >> 6;
    const int tile = blockIdx.x;

    // ---- one-time: stage MLP params (only barrier in the kernel) ----
#pragma unroll
    for (int k = 0; k < 5; ++k) wS[t + 256 * k] = w1[t + 256 * k];
    if (t < 64) { wS[1280 + t] = b1[t]; wS[1344 + t] = w2[t]; }
    if (t == 0) wS[1408] = b2[0];
    __syncthreads();

    // ---- stage this wave's 16 rows of pred (9 global_load_lds) ----
    const float* gp  = pred + (size_t)tile * 8448 + wv * 2112;
    float*       buf = predS + wv * 2112;
#pragma unroll
    for (int k = 0; k < 8; ++k) {
        __builtin_amdgcn_global_load_lds((glb_u32_t*)(gp + 256 * k + 4 * lane),
                                         (lds_u32_t*)(buf + 256 * k), 16, 0, 0);
    }
    __builtin_amdgcn_global_load_lds((glb_u32_t*)(gp + 2048 + lane),
                                     (lds_u32_t*)(buf + 2048), 4, 0, 0);

    // per-wave wait: pred chunk resident; rule-18 fence so ds_reads can't hoist
    asm volatile("s_waitcnt vmcnt(0)" ::: "memory");
    __builtin_amdgcn_sched_barrier(0);

    // ---- scores prefetch (issued now, consumed at the end -> hidden by compute) ----
    const size_t s4 = (size_t)tile * 1280 + wv * 320;   // float4 index
    const float4* sp = reinterpret_cast<const float4*>(scores) + s4;
    float4 sv0 = sp[lane +   0];
    float4 sv1 = sp[lane +  64];
    float4 sv2 = sp[lane + 128];
    float4 sv3 = sp[lane + 192];
    float4 sv4 = sp[lane + 256];

    // ---- compute: thread (r = lane>>2, c = lane&3) owns one corner ----
    const int r = lane >> 2, c = lane & 3;
    const float* xp = buf + r * 132 + c * 33;   // bank = (4r+c+j)%32 -> 2-way, free
    float xs[33];
#pragma unroll
    for (int j = 0; j < 33; ++j) xs[j] = xp[j];

    // branchless top-4 (sorted desc)
    float t0 = -1e30f, t1 = -1e30f, t2 = -1e30f, t3 = -1e30f;
#pragma unroll
    for (int j = 0; j < 33; ++j) {
        float v  = xs[j];
        float r0 = fminf(t0, v);  t0 = fmaxf(t0, v);
        float r1 = fminf(t1, r0); t1 = fmaxf(t1, r0);
        float r2 = fminf(t2, r1); t2 = fmaxf(t2, r1);
        t3 = fmaxf(t3, r2);
    }
    float denom = 0.f;
#pragma unroll
    for (int j = 0; j < 33; ++j)
        denom += __builtin_amdgcn_exp2f((xs[j] - t0) * LOG2E);
    float rd = __builtin_amdgcn_rcpf(denom);

    float s5[5];
    s5[0] = rd;
    s5[1] = __builtin_amdgcn_exp2f((t1 - t0) * LOG2E) * rd;
    s5[2] = __builtin_amdgcn_exp2f((t2 - t0) * LOG2E) * rd;
    s5[3] = __builtin_amdgcn_exp2f((t3 - t0) * LOG2E) * rd;
    s5[4] = (s5[0] + s5[1] + s5[2] + s5[3]) * 0.25f;

    // quad-local exchange: every thread gets all 20 stats of its row
    float stat[20];
#pragma unroll
    for (int i = 0; i < 20; ++i)
        stat[i] = __shfl(s5[i % 5], i / 5, 4);   // width-4 broadcast within quad

    // MLP: thread c computes hidden units [16c..16c+15]
    float hacc[16];
    {
        const float4* b1v = reinterpret_cast<const float4*>(wS + 1280 + 16 * c);
#pragma unroll
        for (int k = 0; k < 4; ++k) {
            float4 b = b1v[k];
            hacc[4*k+0]=b.x; hacc[4*k+1]=b.y; hacc[4*k+2]=b.z; hacc[4*k+3]=b.w;
        }
    }
#pragma unroll
    for (int i = 0; i < 20; ++i) {
        const float si = stat[i];
        const float4* wv4 = reinterpret_cast<const float4*>(wS + i * 64 + 16 * c);
#pragma unroll
        for (int k = 0; k < 4; ++k) {
            float4 w = wv4[k];
            hacc[4*k+0] = fmaf(si, w.x, hacc[4*k+0]);
            hacc[4*k+1] = fmaf(si, w.y, hacc[4*k+1]);
            hacc[4*k+2] = fmaf(si, w.z, hacc[4*k+2]);
            hacc[4*k+3] = fmaf(si, w.w, hacc[4*k+3]);
        }
    }
    float q = 0.f;
    {
        const float4* w2v = reinterpret_cast<const float4*>(wS + 1344 + 16 * c);
#pragma unroll
        for (int k = 0; k < 4; ++k) {
            float4 w = w2v[k];
#pragma unroll
            for (int e = 0; e < 4; ++e) {
                float v  = hacc[4*k+e];
                float sg = __builtin_amdgcn_rcpf(1.f + __builtin_amdgcn_exp2f(-v * LOG2E));
                float we = (e == 0) ? w.x : (e == 1) ? w.y : (e == 2) ? w.z : w.w;
                q = fmaf(v * sg, we, q);
            }
        }
    }
    q += __shfl_xor(q, 1, 4);
    q += __shfl_xor(q, 2, 4);      // all 4 lanes of the quad now hold the row's sum
    q += wS[1408];

    // ---- epilogue: wave writes its own 320 float4 of out = scores + q ----
    float4* op = reinterpret_cast<float4*>(out) + s4;
    {
        float qq; int idx, rl;
        idx = lane +   0; rl = idx / 20; qq = __shfl(q, rl * 4, 64);
        sv0.x+=qq; sv0.y+=qq; sv0.z+=qq; sv0.w+=qq; op[idx] = sv0;
        idx = lane +  64; rl = idx / 20; qq = __shfl(q, rl * 4, 64);
        sv1.x+=qq; sv1.y+=qq; sv1.z+=qq; sv1.w+=qq; op[idx] = sv1;
        idx = lane + 128; rl = idx / 20; qq = __shfl(q, rl * 4, 64);
        sv2.x+=qq; sv2.y+=qq; sv2.z+=qq; sv2.w+=qq; op[idx] = sv2;
        idx = lane + 192; rl = idx / 20; qq = __shfl(q, rl * 4, 64);
        sv3.x+=qq; sv3.y+=qq; sv3.z+=qq; sv3.w+=qq; op[idx] = sv3;
        idx = lane + 256; rl = idx / 20; qq = __shfl(q, rl * 4, 64);
        sv4.x+=qq; sv4.y+=qq; sv4.z+=qq; sv4.w+=qq; op[idx] = sv4;
    }
}

extern "C" void kernel_launch(void* const* d_in, const int* in_sizes, int n_in,
                              void* d_out, int out_size, void* d_ws, size_t ws_size,
                              hipStream_t stream) {
    const float* scores = (const float*)d_in[0];
    const float* pred   = (const float*)d_in[1];
    const float* w1     = (const float*)d_in[2];
    const float* b1     = (const float*)d_in[3];
    const float* w2     = (const float*)d_in[4];
    const float* b2     = (const float*)d_in[5];
    float* out = (float*)d_out;

    const int nrows = in_sizes[1] / 132;   // 800000 = 12500 * 64
    const int grid  = nrows / 64;

    hipLaunchKernelGGL(lqe_wave, dim3(grid), dim3(256), 0, stream,
                       scores, pred, w1, b1, w2, b2, out);
}

// Round 6
// 170.166 us; speedup vs baseline: 1.1913x; 1.0140x over previous
//
#include <hip/hip_runtime.h>

#define LOG2E 1.4426950408889634f

typedef __attribute__((address_space(3))) unsigned int lds_u32_t;
typedef const __attribute__((address_space(1))) unsigned int glb_u32_t;
typedef __fp16 h2 __attribute__((ext_vector_type(2)));
typedef __fp16 h8 __attribute__((ext_vector_type(8)));

// Block = 256 threads = 4 independent waves; each wave owns 16 rows.
// Per wave: stage own pred chunk via global_load_lds -> per-wave vmcnt(0)
// (no block barrier in hot path) -> 4 threads/row topk+softmax -> f16-dot2 MLP.
__global__ __launch_bounds__(256) void lqe_wave6(
    const float* __restrict__ scores,
    const float* __restrict__ pred,
    const float* __restrict__ w1,   // [20][64]
    const float* __restrict__ b1,   // [64]
    const float* __restrict__ w2,   // [64]
    const float* __restrict__ b2,   // [1]
    float* __restrict__ out)
{
    __shared__ __align__(16) float predS[4 * 2112];  // 33792 B, linear per-wave chunks
    __shared__ __align__(16) h2    wH[640];          // wH[p*64+h] = (w1[2p][h], w1[2p+1][h])
    __shared__ __align__(16) float wSf[132];         // b1[0..63] w2[64..127] b2[128]

    const int t    = threadIdx.x;
    const int lane = t & 63;
    const int wv   = t >> 6;
    const int tile = blockIdx.x;

    // ---- one-time: pack w1 to f16 pairs + stage b1/w2/b2 (only barrier) ----
    for (int e = t; e < 640; e += 256) {            // 640 half2 entries
        const int p = e >> 6, h = e & 63;
        float a = w1[p * 128 + h];                  // w1[2p][h]
        float b = w1[p * 128 + 64 + h];             // w1[2p+1][h]
        wH[e] = __builtin_amdgcn_cvt_pkrtz(a, b);
    }
    if (t < 64) { wSf[t] = b1[t]; wSf[64 + t] = w2[t]; }
    if (t == 0) wSf[128] = b2[0];
    __syncthreads();

    // ---- stage this wave's 16 rows of pred (9 global_load_lds) ----
    const float* gp  = pred + (size_t)tile * 8448 + wv * 2112;
    float*       buf = predS + wv * 2112;
#pragma unroll
    for (int k = 0; k < 8; ++k) {
        __builtin_amdgcn_global_load_lds((glb_u32_t*)(gp + 256 * k + 4 * lane),
                                         (lds_u32_t*)(buf + 256 * k), 16, 0, 0);
    }
    __builtin_amdgcn_global_load_lds((glb_u32_t*)(gp + 2048 + lane),
                                     (lds_u32_t*)(buf + 2048), 4, 0, 0);

    // per-wave wait; rule-18 fence so dependent ds_reads can't hoist above it
    asm volatile("s_waitcnt vmcnt(0)" ::: "memory");
    __builtin_amdgcn_sched_barrier(0);

    // ---- scores prefetch (consumed at the end -> latency hidden by compute) ----
    const size_t s4 = (size_t)tile * 1280 + wv * 320;   // float4 index
    const float4* sp = reinterpret_cast<const float4*>(scores) + s4;
    float4 sv0 = sp[lane +   0];
    float4 sv1 = sp[lane +  64];
    float4 sv2 = sp[lane + 128];
    float4 sv3 = sp[lane + 192];
    float4 sv4 = sp[lane + 256];

    // ---- thread (r = lane>>2, c = lane&3) owns one corner of one row ----
    const int r = lane >> 2, c = lane & 3;
    const float* xp = buf + r * 132 + c * 33;   // bank = (lane + j) % 32 -> 2-way, free
    float xs[33];
#pragma unroll
    for (int j = 0; j < 33; ++j) xs[j] = xp[j];

    // branchless top-4 (sorted desc)
    float t0 = -1e30f, t1 = -1e30f, t2 = -1e30f, t3 = -1e30f;
#pragma unroll
    for (int j = 0; j < 33; ++j) {
        float v  = xs[j];
        float r0 = fminf(t0, v);  t0 = fmaxf(t0, v);
        float r1 = fminf(t1, r0); t1 = fmaxf(t1, r0);
        float r2 = fminf(t2, r1); t2 = fmaxf(t2, r1);
        t3 = fmaxf(t3, r2);
    }
    float denom = 0.f;
#pragma unroll
    for (int j = 0; j < 33; ++j)
        denom += __builtin_amdgcn_exp2f((xs[j] - t0) * LOG2E);
    float rd = __builtin_amdgcn_rcpf(denom);

    float s5[5];
    s5[0] = rd;
    s5[1] = __builtin_amdgcn_exp2f((t1 - t0) * LOG2E) * rd;
    s5[2] = __builtin_amdgcn_exp2f((t2 - t0) * LOG2E) * rd;
    s5[3] = __builtin_amdgcn_exp2f((t3 - t0) * LOG2E) * rd;
    s5[4] = (s5[0] + s5[1] + s5[2] + s5[3]) * 0.25f;

    // quad-local exchange: every thread gets all 20 stats of its row
    float stat[20];
#pragma unroll
    for (int i = 0; i < 20; ++i)
        stat[i] = __shfl(s5[i % 5], i / 5, 4);   // width-4 broadcast within quad

    // pack stats into 10 half2 (RTZ pack, 1 instr per pair)
    h2 spk[10];
#pragma unroll
    for (int p = 0; p < 10; ++p)
        spk[p] = __builtin_amdgcn_cvt_pkrtz(stat[2 * p], stat[2 * p + 1]);

    // MLP: thread c computes hidden units [16c..16c+15] via v_dot2_f32_f16
    float hacc[16];
    {
        const float4* b1v = reinterpret_cast<const float4*>(wSf + 16 * c);
#pragma unroll
        for (int k = 0; k < 4; ++k) {
            float4 b = b1v[k];
            hacc[4*k+0]=b.x; hacc[4*k+1]=b.y; hacc[4*k+2]=b.z; hacc[4*k+3]=b.w;
        }
    }
#pragma unroll
    for (int p = 0; p < 10; ++p) {
        const h8* wp = reinterpret_cast<const h8*>(wH + p * 64 + 16 * c);  // 16 h2 = 4 x b128
#pragma unroll
        for (int k = 0; k < 4; ++k) {
            h8 w8 = wp[k];
#pragma unroll
            for (int e = 0; e < 4; ++e) {
                h2 w; w[0] = w8[2*e]; w[1] = w8[2*e+1];
#if __has_builtin(__builtin_amdgcn_fdot2)
                hacc[4*k+e] = __builtin_amdgcn_fdot2(spk[p], w, hacc[4*k+e], false);
#else
                hacc[4*k+e] = fmaf((float)spk[p][0], (float)w[0],
                              fmaf((float)spk[p][1], (float)w[1], hacc[4*k+e]));
#endif
            }
        }
    }

    float q = 0.f;
    {
        const float4* w2v = reinterpret_cast<const float4*>(wSf + 64 + 16 * c);
#pragma unroll
        for (int k = 0; k < 4; ++k) {
            float4 w = w2v[k];
#pragma unroll
            for (int e = 0; e < 4; ++e) {
                float v  = hacc[4*k+e];
                float sg = __builtin_amdgcn_rcpf(1.f + __builtin_amdgcn_exp2f(-v * LOG2E));
                float we = (e == 0) ? w.x : (e == 1) ? w.y : (e == 2) ? w.z : w.w;
                q = fmaf(v * sg, we, q);
            }
        }
    }
    q += __shfl_xor(q, 1, 4);
    q += __shfl_xor(q, 2, 4);      // all 4 lanes of the quad hold the row's sum
    q += wSf[128];

    // ---- epilogue: wave writes its own 320 float4 of out = scores + q ----
    float4* op = reinterpret_cast<float4*>(out) + s4;
    {
        float qq; int idx, rl;
        idx = lane +   0; rl = idx / 20; qq = __shfl(q, rl * 4, 64);
        sv0.x+=qq; sv0.y+=qq; sv0.z+=qq; sv0.w+=qq; op[idx] = sv0;
        idx = lane +  64; rl = idx / 20; qq = __shfl(q, rl * 4, 64);
        sv1.x+=qq; sv1.y+=qq; sv1.z+=qq; sv1.w+=qq; op[idx] = sv1;
        idx = lane + 128; rl = idx / 20; qq = __shfl(q, rl * 4, 64);
        sv2.x+=qq; sv2.y+=qq; sv2.z+=qq; sv2.w+=qq; op[idx] = sv2;
        idx = lane + 192; rl = idx / 20; qq = __shfl(q, rl * 4, 64);
        sv3.x+=qq; sv3.y+=qq; sv3.z+=qq; sv3.w+=qq; op[idx] = sv3;
        idx = lane + 256; rl = idx / 20; qq = __shfl(q, rl * 4, 64);
        sv4.x+=qq; sv4.y+=qq; sv4.z+=qq; sv4.w+=qq; op[idx] = sv4;
    }
}

extern "C" void kernel_launch(void* const* d_in, const int* in_sizes, int n_in,
                              void* d_out, int out_size, void* d_ws, size_t ws_size,
                              hipStream_t stream) {
    const float* scores = (const float*)d_in[0];
    const float* pred   = (const float*)d_in[1];
    const float* w1     = (const float*)d_in[2];
    const float* b1     = (const float*)d_in[3];
    const float* w2     = (const float*)d_in[4];
    const float* b2     = (const float*)d_in[5];
    float* out = (float*)d_out;

    const int nrows = in_sizes[1] / 132;   // 800000 = 12500 * 64
    const int grid  = nrows / 64;

    hipLaunchKernelGGL(lqe_wave6, dim3(grid), dim3(256), 0, stream,
                       scores, pred, w1, b1, w2, b2, out);
}